// Round 1
// baseline (211.319 us; speedup 1.0000x reference)
//
#include <hip/hip_runtime.h>

#define M_B   8192
#define K_IN  784
#define KPAD  800
#define N_H   4096
#define N_OUT 10

typedef __attribute__((ext_vector_type(8))) short bf16x8;
typedef __attribute__((ext_vector_type(4))) float f32x4;
typedef unsigned short u16;
typedef unsigned int   u32;

__device__ __forceinline__ u16 f2bf(float f) {
    union { float f; u32 u; } v; v.f = f;
    u32 r = (v.u + 0x7fffu + ((v.u >> 16) & 1u)) >> 16;
    return (u16)r;
}
__device__ __forceinline__ float bf2f(u16 h) {
    union { u32 u; float f; } v; v.u = ((u32)h) << 16;
    return v.f;
}
__device__ __forceinline__ void load_lds16(const void* g, void* l) {
    __builtin_amdgcn_global_load_lds(
        (const __attribute__((address_space(1))) void*)g,
        (__attribute__((address_space(3))) void*)l, 16, 0, 0);
}
// signed byte i (0..3) of 32-bit word -> float
__device__ __forceinline__ float sb(int w, int i) {
    return (float)((w << (24 - 8 * i)) >> 24);
}

// ---- prep: x fp32[8192][784] -> bf16[8192][800] zero-padded ----
__global__ void prep_x(const float* __restrict__ x, u16* __restrict__ xb) {
    int idx = blockIdx.x * 256 + threadIdx.x;       // 8192*100 groups of 8
    if (idx >= M_B * 100) return;
    int row = idx / 100;
    int col = (idx - row * 100) * 8;
    u16 v[8];
    if (col < K_IN) {
        const float4* p = (const float4*)(x + (size_t)row * K_IN + col);
        float4 a = p[0], b = p[1];
        v[0] = f2bf(a.x); v[1] = f2bf(a.y); v[2] = f2bf(a.z); v[3] = f2bf(a.w);
        v[4] = f2bf(b.x); v[5] = f2bf(b.y); v[6] = f2bf(b.z); v[7] = f2bf(b.w);
    } else {
        #pragma unroll
        for (int i = 0; i < 8; ++i) v[i] = 0;
    }
    *(uint4*)(xb + (size_t)row * KPAD + col) = *(const uint4*)v;
}

// ---- prep: w1 fp32[4096][784] -> ternary bf16[4096][800] ----
__global__ void prep_w1(const float* __restrict__ w, u16* __restrict__ wb) {
    int idx = blockIdx.x * 256 + threadIdx.x;       // 4096*100
    if (idx >= N_H * 100) return;
    int row = idx / 100;
    int col = (idx - row * 100) * 8;
    u16 v[8];
    if (col < K_IN) {
        const float* p = w + (size_t)row * K_IN + col;
        #pragma unroll
        for (int i = 0; i < 8; ++i) {
            float f = p[i];
            v[i] = f > 0.1f ? 0x3F80u : (f < -0.1f ? 0xBF80u : 0u);
        }
    } else {
        #pragma unroll
        for (int i = 0; i < 8; ++i) v[i] = 0;
    }
    *(uint4*)(wb + (size_t)row * KPAD + col) = *(const uint4*)v;
}

// ---- prep: w2 fp32[10][4096] -> ternary int8 [4096][16] (k-major rows), zero maxbuf ----
__global__ void prep_w2(const float* __restrict__ w2, signed char* __restrict__ w2c,
                        u32* __restrict__ maxb) {
    int k = blockIdx.x * 256 + threadIdx.x;
    if (k == 0) *maxb = 0u;
    if (k >= N_H) return;
    signed char v[16];
    #pragma unroll
    for (int o = 0; o < 16; ++o) v[o] = 0;
    #pragma unroll
    for (int o = 0; o < N_OUT; ++o) {
        float f = w2[(size_t)o * N_H + k];
        v[o] = f > 0.1f ? 1 : (f < -0.1f ? -1 : 0);
    }
    *(int4*)(w2c + (size_t)k * 16) = *(const int4*)v;
}

// ---- GEMM1: h = relu(x @ w1q^T + b1), bf16 store + global absmax ----
__global__ __launch_bounds__(256) void gemm1(
    const u16* __restrict__ A,   // xb  [M_B][KPAD]
    const u16* __restrict__ Bw,  // w1b [N_H][KPAD]
    const float* __restrict__ b1,
    u16* __restrict__ H,         // out [M_B][N_H] bf16
    u32* __restrict__ maxb)
{
    __shared__ __align__(16) u16 As[128 * 32];
    __shared__ __align__(16) u16 Bs[128 * 32];
    __shared__ float wmax[4];

    const int tid  = threadIdx.x;
    const int lane = tid & 63;
    const int wave = tid >> 6;
    const int wr = wave >> 1, wc = wave & 1;
    const int bm = blockIdx.x, bn = blockIdx.y;

    f32x4 acc[4][4] = {};

    // staging: thread t covers flat elems [t*8, t*8+8) and [(256+t)*8, ...)
    const int r0 = tid >> 2;
    const int c0 = (tid & 3) << 3;
    const u16* ga0 = A  + (size_t)(bm * 128 + r0) * KPAD + c0;
    const u16* ga1 = ga0 + (size_t)64 * KPAD;
    const u16* gb0 = Bw + (size_t)(bn * 128 + r0) * KPAD + c0;
    const u16* gb1 = gb0 + (size_t)64 * KPAD;
    u16* la0 = &As[tid * 8];
    u16* la1 = &As[(256 + tid) * 8];
    u16* lb0 = &Bs[tid * 8];
    u16* lb1 = &Bs[(256 + tid) * 8];

    const u16* pa = &As[(wr * 64 + (lane & 15)) * 32 + ((lane >> 4) << 3)];
    const u16* pb = &Bs[(wc * 64 + (lane & 15)) * 32 + ((lane >> 4) << 3)];

    for (int k0 = 0; k0 < KPAD; k0 += 32) {
        load_lds16(ga0, la0); load_lds16(ga1, la1);
        load_lds16(gb0, lb0); load_lds16(gb1, lb1);
        ga0 += 32; ga1 += 32; gb0 += 32; gb1 += 32;
        __syncthreads();   // drains vmcnt -> LDS visible

        bf16x8 af[4], bfr[4];
        #pragma unroll
        for (int i = 0; i < 4; ++i) af[i]  = *(const bf16x8*)(pa + i * 512);
        #pragma unroll
        for (int j = 0; j < 4; ++j) bfr[j] = *(const bf16x8*)(pb + j * 512);
        #pragma unroll
        for (int i = 0; i < 4; ++i)
            #pragma unroll
            for (int j = 0; j < 4; ++j)
                acc[i][j] = __builtin_amdgcn_mfma_f32_16x16x32_bf16(
                    af[i], bfr[j], acc[i][j], 0, 0, 0);
        __syncthreads();   // all waves done reading before next overwrite
    }

    // epilogue: + b1, relu, bf16 store, local max
    const int colbase = bn * 128 + wc * 64 + (lane & 15);
    float bias[4];
    #pragma unroll
    for (int j = 0; j < 4; ++j) bias[j] = b1[colbase + j * 16];

    float lmax = 0.f;
    #pragma unroll
    for (int i = 0; i < 4; ++i) {
        int rowb = bm * 128 + wr * 64 + i * 16 + ((lane >> 4) << 2);
        #pragma unroll
        for (int r = 0; r < 4; ++r) {
            size_t off = (size_t)(rowb + r) * N_H + colbase;
            #pragma unroll
            for (int j = 0; j < 4; ++j) {
                float v = acc[i][j][r] + bias[j];
                v = fmaxf(v, 0.f);
                lmax = fmaxf(lmax, v);
                H[off + j * 16] = f2bf(v);
            }
        }
    }
    #pragma unroll
    for (int s = 32; s; s >>= 1) lmax = fmaxf(lmax, __shfl_down(lmax, s, 64));
    if (lane == 0) wmax[wave] = lmax;
    __syncthreads();
    if (tid == 0)
        atomicMax(maxb, __float_as_uint(
            fmaxf(fmaxf(wmax[0], wmax[1]), fmaxf(wmax[2], wmax[3]))));
}

// ---- GEMM2: quantize h, logits = hq @ w2q^T + b2, log_softmax ----
__global__ __launch_bounds__(256) void gemm2_lsm(
    const u16* __restrict__ H,
    const signed char* __restrict__ W2c,  // [4096][16]
    const float* __restrict__ b2,
    const u32* __restrict__ maxb,
    float* __restrict__ out)
{
    const int wave = threadIdx.x >> 6;
    const int lane = threadIdx.x & 63;
    const int row0 = blockIdx.x * 16 + wave * 4;   // 4 rows per wave

    const float maxv  = __uint_as_float(*maxb);
    const float scale = 127.0f / maxv;
    const float invs  = 1.0f / scale;

    float bb[10];
    #pragma unroll
    for (int o = 0; o < N_OUT; ++o) bb[o] = b2[o];

    float s[4][10];
    #pragma unroll
    for (int r = 0; r < 4; ++r)
        #pragma unroll
        for (int o = 0; o < N_OUT; ++o) s[r][o] = 0.f;

    for (int it = 0; it < 64; ++it) {
        const int k = it * 64 + lane;
        const int4 wv = *(const int4*)(W2c + (size_t)k * 16);
        float w[10];
        w[0] = sb(wv.x, 0); w[1] = sb(wv.x, 1); w[2] = sb(wv.x, 2); w[3] = sb(wv.x, 3);
        w[4] = sb(wv.y, 0); w[5] = sb(wv.y, 1); w[6] = sb(wv.y, 2); w[7] = sb(wv.y, 3);
        w[8] = sb(wv.z, 0); w[9] = sb(wv.z, 1);
        #pragma unroll
        for (int r = 0; r < 4; ++r) {
            float f = bf2f(H[(size_t)(row0 + r) * N_H + k]);
            float q = fminf(rintf(f * scale), 127.0f);  // RNE, matches jnp.round
            #pragma unroll
            for (int o = 0; o < N_OUT; ++o) s[r][o] = fmaf(q, w[o], s[r][o]);
        }
    }

    // 64-lane butterfly reduction
    #pragma unroll
    for (int r = 0; r < 4; ++r)
        #pragma unroll
        for (int o = 0; o < N_OUT; ++o) {
            float v = s[r][o];
            v += __shfl_xor(v, 1, 64);
            v += __shfl_xor(v, 2, 64);
            v += __shfl_xor(v, 4, 64);
            v += __shfl_xor(v, 8, 64);
            v += __shfl_xor(v, 16, 64);
            v += __shfl_xor(v, 32, 64);
            s[r][o] = v;
        }

    if (lane == 0) {
        #pragma unroll
        for (int r = 0; r < 4; ++r) {
            float lg[10], mx = -1e30f;
            #pragma unroll
            for (int o = 0; o < N_OUT; ++o) {
                lg[o] = fmaf(s[r][o], invs, bb[o]);
                mx = fmaxf(mx, lg[o]);
            }
            float se = 0.f;
            #pragma unroll
            for (int o = 0; o < N_OUT; ++o) se += expf(lg[o] - mx);
            float lse = logf(se) + mx;
            #pragma unroll
            for (int o = 0; o < N_OUT; ++o)
                out[(size_t)(row0 + r) * N_OUT + o] = lg[o] - lse;
        }
    }
}

extern "C" void kernel_launch(void* const* d_in, const int* in_sizes, int n_in,
                              void* d_out, int out_size, void* d_ws, size_t ws_size,
                              hipStream_t stream) {
    const float* x  = (const float*)d_in[0];
    const float* w1 = (const float*)d_in[1];
    const float* b1 = (const float*)d_in[2];
    const float* w2 = (const float*)d_in[3];
    const float* b2 = (const float*)d_in[4];
    float* out = (float*)d_out;

    // workspace carve (all 256B-aligned offsets); total ~86.8 MB
    char* ws = (char*)d_ws;
    u16* xb  = (u16*)(ws);                         // 8192*800*2  = 13,107,200
    u16* w1b = (u16*)(ws + 13107200);              // 4096*800*2  =  6,553,600
    u16* hb  = (u16*)(ws + 19660800);              // 8192*4096*2 = 67,108,864
    signed char* w2c = (signed char*)(ws + 86769664); // 4096*16   =     65,536
    u32* maxb = (u32*)(ws + 86835200);             // 4

    prep_x <<<3200, 256, 0, stream>>>(x,  xb);
    prep_w1<<<1600, 256, 0, stream>>>(w1, w1b);
    prep_w2<<<16,   256, 0, stream>>>(w2, w2c, maxb);
    gemm1  <<<dim3(64, 32), 256, 0, stream>>>(xb, w1b, b1, hb, maxb);
    gemm2_lsm<<<512, 256, 0, stream>>>(hb, w2c, b2, maxb, out);
}

// Round 2
// 202.059 us; speedup vs baseline: 1.0458x; 1.0458x over previous
//
#include <hip/hip_runtime.h>

#define M_B   8192
#define K_IN  784
#define KPAD  800
#define N_H   4096
#define N_OUT 10

typedef __attribute__((ext_vector_type(8))) short bf16x8;
typedef __attribute__((ext_vector_type(4))) float f32x4;
typedef unsigned short u16;
typedef unsigned int   u32;

__device__ __forceinline__ u16 f2bf(float f) {
    union { float f; u32 u; } v; v.f = f;
    u32 r = (v.u + 0x7fffu + ((v.u >> 16) & 1u)) >> 16;
    return (u16)r;
}
__device__ __forceinline__ float bf2f(u16 h) {
    union { u32 u; float f; } v; v.u = ((u32)h) << 16;
    return v.f;
}
__device__ __forceinline__ void load_lds16(const void* g, void* l) {
    __builtin_amdgcn_global_load_lds(
        (const __attribute__((address_space(1))) void*)g,
        (__attribute__((address_space(3))) void*)l, 16, 0, 0);
}
// signed byte i (0..3) of 32-bit word -> float
__device__ __forceinline__ float sb(int w, int i) {
    return (float)((w << (24 - 8 * i)) >> 24);
}

// ---- merged prep: x->bf16[8192][800], w1->tern bf16[4096][800],
//      w2->tern int8[4096][16], maxb<-0. One launch instead of three. ----
__global__ void prep_all(const float* __restrict__ x, const float* __restrict__ w1,
                         const float* __restrict__ w2,
                         u16* __restrict__ xb, u16* __restrict__ w1b,
                         signed char* __restrict__ w2c, u32* __restrict__ maxb) {
    const int blk = blockIdx.x;
    const int tid = threadIdx.x;
    if (blk < 3200) {                       // ---- x ----
        int idx = blk * 256 + tid;          // 8192*100 groups of 8
        int row = idx / 100;
        int col = (idx - row * 100) * 8;
        u16 v[8];
        if (col < K_IN) {
            const float4* p = (const float4*)(x + (size_t)row * K_IN + col);
            float4 a = p[0], b = p[1];
            v[0] = f2bf(a.x); v[1] = f2bf(a.y); v[2] = f2bf(a.z); v[3] = f2bf(a.w);
            v[4] = f2bf(b.x); v[5] = f2bf(b.y); v[6] = f2bf(b.z); v[7] = f2bf(b.w);
        } else {
            #pragma unroll
            for (int i = 0; i < 8; ++i) v[i] = 0;
        }
        *(uint4*)(xb + (size_t)row * KPAD + col) = *(const uint4*)v;
    } else if (blk < 4800) {                // ---- w1 ternary ----
        int idx = (blk - 3200) * 256 + tid; // 4096*100
        int row = idx / 100;
        int col = (idx - row * 100) * 8;
        u16 v[8];
        if (col < K_IN) {
            const float* p = w1 + (size_t)row * K_IN + col;
            #pragma unroll
            for (int i = 0; i < 8; ++i) {
                float f = p[i];
                v[i] = f > 0.1f ? 0x3F80u : (f < -0.1f ? 0xBF80u : 0u);
            }
        } else {
            #pragma unroll
            for (int i = 0; i < 8; ++i) v[i] = 0;
        }
        *(uint4*)(w1b + (size_t)row * KPAD + col) = *(const uint4*)v;
    } else {                                // ---- w2 ternary int8, k-major ----
        int k = (blk - 4800) * 256 + tid;
        if (k == 0) *maxb = 0u;
        if (k >= N_H) return;
        signed char v[16];
        #pragma unroll
        for (int o = 0; o < 16; ++o) v[o] = 0;
        #pragma unroll
        for (int o = 0; o < N_OUT; ++o) {
            float f = w2[(size_t)o * N_H + k];
            v[o] = f > 0.1f ? 1 : (f < -0.1f ? -1 : 0);
        }
        *(int4*)(w2c + (size_t)k * 16) = *(const int4*)v;
    }
}

// ---- GEMM1: Ht[col][row] = relu(x @ w1q^T + b1) (TRANSPOSED), bf16 + absmax ----
__global__ __launch_bounds__(256) void gemm1(
    const u16* __restrict__ A,   // xb  [M_B][KPAD]
    const u16* __restrict__ Bw,  // w1b [N_H][KPAD]
    const float* __restrict__ b1,
    u16* __restrict__ Ht,        // out [N_H][M_B] bf16 (transposed)
    u32* __restrict__ maxb)
{
    __shared__ __align__(16) u16 As[128 * 32];
    __shared__ __align__(16) u16 Bs[128 * 32];
    __shared__ float wmax[4];

    const int tid  = threadIdx.x;
    const int lane = tid & 63;
    const int wave = tid >> 6;
    const int wr = wave >> 1, wc = wave & 1;
    const int bm = blockIdx.x, bn = blockIdx.y;

    f32x4 acc[4][4] = {};

    const int r0 = tid >> 2;
    const int c0 = (tid & 3) << 3;
    const u16* ga0 = A  + (size_t)(bm * 128 + r0) * KPAD + c0;
    const u16* ga1 = ga0 + (size_t)64 * KPAD;
    const u16* gb0 = Bw + (size_t)(bn * 128 + r0) * KPAD + c0;
    const u16* gb1 = gb0 + (size_t)64 * KPAD;
    u16* la0 = &As[tid * 8];
    u16* la1 = &As[(256 + tid) * 8];
    u16* lb0 = &Bs[tid * 8];
    u16* lb1 = &Bs[(256 + tid) * 8];

    const u16* pa = &As[(wr * 64 + (lane & 15)) * 32 + ((lane >> 4) << 3)];
    const u16* pb = &Bs[(wc * 64 + (lane & 15)) * 32 + ((lane >> 4) << 3)];

    for (int k0 = 0; k0 < KPAD; k0 += 32) {
        load_lds16(ga0, la0); load_lds16(ga1, la1);
        load_lds16(gb0, lb0); load_lds16(gb1, lb1);
        ga0 += 32; ga1 += 32; gb0 += 32; gb1 += 32;
        __syncthreads();

        bf16x8 af[4], bfr[4];
        #pragma unroll
        for (int i = 0; i < 4; ++i) af[i]  = *(const bf16x8*)(pa + i * 512);
        #pragma unroll
        for (int j = 0; j < 4; ++j) bfr[j] = *(const bf16x8*)(pb + j * 512);
        #pragma unroll
        for (int i = 0; i < 4; ++i)
            #pragma unroll
            for (int j = 0; j < 4; ++j)
                acc[i][j] = __builtin_amdgcn_mfma_f32_16x16x32_bf16(
                    af[i], bfr[j], acc[i][j], 0, 0, 0);
        __syncthreads();
    }

    // epilogue: +b1, relu, bf16, TRANSPOSED store (4 consecutive rows/lane = uint2)
    const int colb = bn * 128 + wc * 64 + (lane & 15);
    const int rowb = bm * 128 + wr * 64 + ((lane >> 4) << 2);

    float lmax = 0.f;
    #pragma unroll
    for (int j = 0; j < 4; ++j) {
        const int col = colb + j * 16;
        const float bias = b1[col];
        u16* hp = Ht + (size_t)col * M_B + rowb;
        #pragma unroll
        for (int i = 0; i < 4; ++i) {
            u32 pk[2];
            #pragma unroll
            for (int h = 0; h < 2; ++h) {
                float v0 = fmaxf(acc[i][j][2 * h]     + bias, 0.f);
                float v1 = fmaxf(acc[i][j][2 * h + 1] + bias, 0.f);
                lmax = fmaxf(lmax, fmaxf(v0, v1));
                pk[h] = (u32)f2bf(v0) | ((u32)f2bf(v1) << 16);
            }
            *(uint2*)(hp + i * 16) = make_uint2(pk[0], pk[1]);
        }
    }
    #pragma unroll
    for (int s = 32; s; s >>= 1) lmax = fmaxf(lmax, __shfl_down(lmax, s, 64));
    if (lane == 0) wmax[wave] = lmax;
    __syncthreads();
    if (tid == 0)
        atomicMax(maxb, __float_as_uint(
            fmaxf(fmaxf(wmax[0], wmax[1]), fmaxf(wmax[2], wmax[3]))));
}

// ---- GEMM2 partials: split-K, lane owns 2 batch rows, no reduction ----
// grid (16 bx, 32 ky); part[ky][b][10] fp32
__global__ __launch_bounds__(256) void gemm2_part(
    const u16* __restrict__ Ht,
    const signed char* __restrict__ W2c,
    const u32* __restrict__ maxb,
    float* __restrict__ part)
{
    __shared__ int4 sW[128];
    const int tid = threadIdx.x;
    const int bx = blockIdx.x;
    const int ky = blockIdx.y;
    if (tid < 128) sW[tid] = *(const int4*)(W2c + (size_t)(ky * 128 + tid) * 16);
    const float scale = 127.0f / __uint_as_float(*maxb);
    __syncthreads();

    const int b0 = bx * 512 + tid * 2;
    float s0[N_OUT] = {}, s1[N_OUT] = {};
    const u16* hp = Ht + (size_t)(ky * 128) * M_B + b0;

    #pragma unroll 4
    for (int kk = 0; kk < 128; ++kk) {
        const int4 wv = sW[kk];
        float w[N_OUT];
        w[0] = sb(wv.x, 0); w[1] = sb(wv.x, 1); w[2] = sb(wv.x, 2); w[3] = sb(wv.x, 3);
        w[4] = sb(wv.y, 0); w[5] = sb(wv.y, 1); w[6] = sb(wv.y, 2); w[7] = sb(wv.y, 3);
        w[8] = sb(wv.z, 0); w[9] = sb(wv.z, 1);
        const u32 hv = *(const u32*)hp;
        hp += M_B;
        const float q0 = fminf(rintf(bf2f((u16)(hv & 0xffffu)) * scale), 127.0f);
        const float q1 = fminf(rintf(bf2f((u16)(hv >> 16))     * scale), 127.0f);
        #pragma unroll
        for (int o = 0; o < N_OUT; ++o) {
            s0[o] = fmaf(q0, w[o], s0[o]);
            s1[o] = fmaf(q1, w[o], s1[o]);
        }
    }
    float* p = part + ((size_t)ky * M_B + b0) * N_OUT;
    #pragma unroll
    for (int o = 0; o < N_OUT; ++o) { p[o] = s0[o]; p[N_OUT + o] = s1[o]; }
}

// ---- reduce 32 partials + bias + log_softmax; one thread per batch row ----
__global__ __launch_bounds__(256) void lsm_out(
    const float* __restrict__ part,
    const float* __restrict__ b2,
    const u32* __restrict__ maxb,
    float* __restrict__ out)
{
    const int b = blockIdx.x * 256 + threadIdx.x;
    const float invs = __uint_as_float(*maxb) / 127.0f;

    float s[N_OUT] = {};
    for (int p = 0; p < 32; ++p) {
        const float* pp = part + ((size_t)p * M_B + b) * N_OUT;
        #pragma unroll
        for (int o = 0; o < N_OUT; ++o) s[o] += pp[o];
    }
    float lg[N_OUT], mx = -1e30f;
    #pragma unroll
    for (int o = 0; o < N_OUT; ++o) {
        lg[o] = fmaf(s[o], invs, b2[o]);
        mx = fmaxf(mx, lg[o]);
    }
    float se = 0.f;
    #pragma unroll
    for (int o = 0; o < N_OUT; ++o) se += expf(lg[o] - mx);
    const float lse = logf(se) + mx;
    float* op = out + (size_t)b * N_OUT;
    #pragma unroll
    for (int o = 0; o < N_OUT; ++o) op[o] = lg[o] - lse;
}

extern "C" void kernel_launch(void* const* d_in, const int* in_sizes, int n_in,
                              void* d_out, int out_size, void* d_ws, size_t ws_size,
                              hipStream_t stream) {
    const float* x  = (const float*)d_in[0];
    const float* w1 = (const float*)d_in[1];
    const float* b1 = (const float*)d_in[2];
    const float* w2 = (const float*)d_in[3];
    const float* b2 = (const float*)d_in[4];
    float* out = (float*)d_out;

    // workspace carve; part overlays xb (dead after gemm1). total ~86.8 MB
    char* ws = (char*)d_ws;
    u16* xb  = (u16*)(ws);                            // 13,107,200 B
    float* part = (float*)(ws);                       // 10,485,760 B (overlay)
    u16* w1b = (u16*)(ws + 13107200);                 //  6,553,600 B
    u16* ht  = (u16*)(ws + 19660800);                 // 67,108,864 B
    signed char* w2c = (signed char*)(ws + 86769664); //     65,536 B
    u32* maxb = (u32*)(ws + 86835200);                //          4 B

    prep_all<<<4816, 256, 0, stream>>>(x, w1, w2, xb, w1b, w2c, maxb);
    gemm1<<<dim3(64, 32), 256, 0, stream>>>(xb, w1b, b1, ht, maxb);
    gemm2_part<<<dim3(16, 32), 256, 0, stream>>>(ht, w2c, maxb, part);
    lsm_out<<<32, 256, 0, stream>>>(part, b2, maxb, out);
}

// Round 3
// 189.273 us; speedup vs baseline: 1.1165x; 1.0676x over previous
//
#include <hip/hip_runtime.h>

#define M_B   8192
#define K_IN  784
#define KPAD  800
#define N_H   4096
#define N_OUT 10
#define BM    256
#define BN    128
#define BK    32

typedef __attribute__((ext_vector_type(8))) short bf16x8;
typedef __attribute__((ext_vector_type(4))) float f32x4;
typedef unsigned short u16;
typedef unsigned int   u32;

__device__ __forceinline__ u16 f2bf(float f) {
    union { float f; u32 u; } v; v.f = f;
    u32 r = (v.u + 0x7fffu + ((v.u >> 16) & 1u)) >> 16;
    return (u16)r;
}
__device__ __forceinline__ float bf2f(u16 h) {
    union { u32 u; float f; } v; v.u = ((u32)h) << 16;
    return v.f;
}
__device__ __forceinline__ void load_lds16(const void* g, void* l) {
    __builtin_amdgcn_global_load_lds(
        (const __attribute__((address_space(1))) void*)g,
        (__attribute__((address_space(3))) void*)l, 16, 0, 0);
}
__device__ __forceinline__ float sb(int w, int i) {
    return (float)((w << (24 - 8 * i)) >> 24);
}

// ---- merged prep (unchanged from R2) ----
__global__ void prep_all(const float* __restrict__ x, const float* __restrict__ w1,
                         const float* __restrict__ w2,
                         u16* __restrict__ xb, u16* __restrict__ w1b,
                         signed char* __restrict__ w2c, u32* __restrict__ maxb) {
    const int blk = blockIdx.x;
    const int tid = threadIdx.x;
    if (blk < 3200) {                       // ---- x ----
        int idx = blk * 256 + tid;
        int row = idx / 100;
        int col = (idx - row * 100) * 8;
        u16 v[8];
        if (col < K_IN) {
            const float4* p = (const float4*)(x + (size_t)row * K_IN + col);
            float4 a = p[0], b = p[1];
            v[0] = f2bf(a.x); v[1] = f2bf(a.y); v[2] = f2bf(a.z); v[3] = f2bf(a.w);
            v[4] = f2bf(b.x); v[5] = f2bf(b.y); v[6] = f2bf(b.z); v[7] = f2bf(b.w);
        } else {
            #pragma unroll
            for (int i = 0; i < 8; ++i) v[i] = 0;
        }
        *(uint4*)(xb + (size_t)row * KPAD + col) = *(const uint4*)v;
    } else if (blk < 4800) {                // ---- w1 ternary ----
        int idx = (blk - 3200) * 256 + tid;
        int row = idx / 100;
        int col = (idx - row * 100) * 8;
        u16 v[8];
        if (col < K_IN) {
            const float4* p = (const float4*)(w1 + (size_t)row * K_IN + col);
            float4 a = p[0], b = p[1];
            float ff[8] = {a.x, a.y, a.z, a.w, b.x, b.y, b.z, b.w};
            #pragma unroll
            for (int i = 0; i < 8; ++i)
                v[i] = ff[i] > 0.1f ? 0x3F80u : (ff[i] < -0.1f ? 0xBF80u : 0u);
        } else {
            #pragma unroll
            for (int i = 0; i < 8; ++i) v[i] = 0;
        }
        *(uint4*)(w1b + (size_t)row * KPAD + col) = *(const uint4*)v;
    } else {                                // ---- w2 ternary int8, k-major ----
        int k = (blk - 4800) * 256 + tid;
        if (k == 0) *maxb = 0u;
        if (k >= N_H) return;
        signed char v[16];
        #pragma unroll
        for (int o = 0; o < 16; ++o) v[o] = 0;
        #pragma unroll
        for (int o = 0; o < N_OUT; ++o) {
            float f = w2[(size_t)o * N_H + k];
            v[o] = f > 0.1f ? 1 : (f < -0.1f ? -1 : 0);
        }
        *(int4*)(w2c + (size_t)k * 16) = *(const int4*)v;
    }
}

// ---- GEMM1: 256x128 block, 4 waves, wave tile 128x64 (acc 8x4), XOR-swizzled LDS.
//      Ht[col][row] = relu(x @ w1q^T + b1) bf16 + global absmax ----
__global__ __launch_bounds__(256, 2) void gemm1(
    const u16* __restrict__ A,   // xb  [M_B][KPAD]
    const u16* __restrict__ Bw,  // w1b [N_H][KPAD]
    const float* __restrict__ b1,
    u16* __restrict__ Ht,        // [N_H][M_B] bf16 (transposed)
    u32* __restrict__ maxb)
{
    __shared__ __align__(16) u16 As[BM * BK];   // 16 KB
    __shared__ __align__(16) u16 Bs[BN * BK];   //  8 KB
    __shared__ float wmax[4];

    const int tid  = threadIdx.x;
    const int lane = tid & 63;
    const int wave = tid >> 6;
    const int wr = wave >> 1, wc = wave & 1;    // wr: A-half (128 rows), wc: B-half (64 cols)
    const int bm = blockIdx.x, bn = blockIdx.y;

    f32x4 acc[8][4] = {};

    // staging: slot s (16B) holds global (row = s>>2, kchunk = (s&3) ^ ((s>>3)&3))
    const u16* gaP[4]; u16* laP[4];
    #pragma unroll
    for (int j = 0; j < 4; ++j) {
        int s = tid + 256 * j;
        int grow = s >> 2;
        int gcol = (((s & 3) ^ ((s >> 3) & 3)) << 3);
        gaP[j] = A + (size_t)(bm * BM + grow) * KPAD + gcol;
        laP[j] = &As[s * 8];
    }
    const u16* gbP[2]; u16* lbP[2];
    #pragma unroll
    for (int j = 0; j < 2; ++j) {
        int s = tid + 256 * j;
        int grow = s >> 2;
        int gcol = (((s & 3) ^ ((s >> 3) & 3)) << 3);
        gbP[j] = Bw + (size_t)(bn * BN + grow) * KPAD + gcol;
        lbP[j] = &Bs[s * 8];
    }

    // fragment read base: row-dependent swizzled k-chunk, constant per lane
    const int kcp = ((lane >> 4) ^ ((lane >> 1) & 3)) << 3;
    const u16* pa = &As[(wr * 128 + (lane & 15)) * BK + kcp];
    const u16* pb = &Bs[(wc * 64  + (lane & 15)) * BK + kcp];

    for (int k0 = 0; k0 < KPAD; k0 += BK) {
        #pragma unroll
        for (int j = 0; j < 4; ++j) { load_lds16(gaP[j], laP[j]); gaP[j] += BK; }
        #pragma unroll
        for (int j = 0; j < 2; ++j) { load_lds16(gbP[j], lbP[j]); gbP[j] += BK; }
        __syncthreads();

        bf16x8 af[8], bfr[4];
        #pragma unroll
        for (int i = 0; i < 8; ++i) af[i]  = *(const bf16x8*)(pa + i * 512);
        #pragma unroll
        for (int j = 0; j < 4; ++j) bfr[j] = *(const bf16x8*)(pb + j * 512);
        #pragma unroll
        for (int i = 0; i < 8; ++i)
            #pragma unroll
            for (int j = 0; j < 4; ++j)
                acc[i][j] = __builtin_amdgcn_mfma_f32_16x16x32_bf16(
                    af[i], bfr[j], acc[i][j], 0, 0, 0);
        __syncthreads();
    }

    // epilogue: +b1, relu, bf16, transposed store (4 consecutive rows -> uint2)
    const int colb = bn * BN + wc * 64 + (lane & 15);
    const int rowb = bm * BM + wr * 128 + ((lane >> 4) << 2);

    float lmax = 0.f;
    #pragma unroll
    for (int j = 0; j < 4; ++j) {
        const int col = colb + j * 16;
        const float bias = b1[col];
        u16* hp = Ht + (size_t)col * M_B + rowb;
        #pragma unroll
        for (int i = 0; i < 8; ++i) {
            u32 pk[2];
            #pragma unroll
            for (int h = 0; h < 2; ++h) {
                float v0 = fmaxf(acc[i][j][2 * h]     + bias, 0.f);
                float v1 = fmaxf(acc[i][j][2 * h + 1] + bias, 0.f);
                lmax = fmaxf(lmax, fmaxf(v0, v1));
                pk[h] = (u32)f2bf(v0) | ((u32)f2bf(v1) << 16);
            }
            *(uint2*)(hp + i * 16) = make_uint2(pk[0], pk[1]);
        }
    }
    #pragma unroll
    for (int s = 32; s; s >>= 1) lmax = fmaxf(lmax, __shfl_down(lmax, s, 64));
    if (lane == 0) wmax[wave] = lmax;
    __syncthreads();
    if (tid == 0)
        atomicMax(maxb, __float_as_uint(
            fmaxf(fmaxf(wmax[0], wmax[1]), fmaxf(wmax[2], wmax[3]))));
}

// ---- GEMM2 partials: split-K, lane owns 2 batch rows ----
__global__ __launch_bounds__(256) void gemm2_part(
    const u16* __restrict__ Ht,
    const signed char* __restrict__ W2c,
    const u32* __restrict__ maxb,
    float* __restrict__ part)
{
    __shared__ int4 sW[128];
    const int tid = threadIdx.x;
    const int bx = blockIdx.x;
    const int ky = blockIdx.y;
    if (tid < 128) sW[tid] = *(const int4*)(W2c + (size_t)(ky * 128 + tid) * 16);
    const float scale = 127.0f / __uint_as_float(*maxb);
    __syncthreads();

    const int b0 = bx * 512 + tid * 2;
    float s0[N_OUT] = {}, s1[N_OUT] = {};
    const u16* hp = Ht + (size_t)(ky * 128) * M_B + b0;

    #pragma unroll 8
    for (int kk = 0; kk < 128; ++kk) {
        const int4 wv = sW[kk];
        float w[N_OUT];
        w[0] = sb(wv.x, 0); w[1] = sb(wv.x, 1); w[2] = sb(wv.x, 2); w[3] = sb(wv.x, 3);
        w[4] = sb(wv.y, 0); w[5] = sb(wv.y, 1); w[6] = sb(wv.y, 2); w[7] = sb(wv.y, 3);
        w[8] = sb(wv.z, 0); w[9] = sb(wv.z, 1);
        const u32 hv = *(const u32*)hp;
        hp += M_B;
        const float q0 = fminf(rintf(bf2f((u16)(hv & 0xffffu)) * scale), 127.0f);
        const float q1 = fminf(rintf(bf2f((u16)(hv >> 16))     * scale), 127.0f);
        #pragma unroll
        for (int o = 0; o < N_OUT; ++o) {
            s0[o] = fmaf(q0, w[o], s0[o]);
            s1[o] = fmaf(q1, w[o], s1[o]);
        }
    }
    float* p = part + ((size_t)ky * M_B + b0) * N_OUT;
    #pragma unroll
    for (int o = 0; o < N_OUT; ++o) { p[o] = s0[o]; p[N_OUT + o] = s1[o]; }
}

// ---- reduce partials + bias + log_softmax ----
__global__ __launch_bounds__(256) void lsm_out(
    const float* __restrict__ part,
    const float* __restrict__ b2,
    const u32* __restrict__ maxb,
    float* __restrict__ out)
{
    const int b = blockIdx.x * 256 + threadIdx.x;
    const float invs = __uint_as_float(*maxb) / 127.0f;

    float s[N_OUT] = {};
    for (int p = 0; p < 32; ++p) {
        const float* pp = part + ((size_t)p * M_B + b) * N_OUT;
        #pragma unroll
        for (int o = 0; o < N_OUT; ++o) s[o] += pp[o];
    }
    float lg[N_OUT], mx = -1e30f;
    #pragma unroll
    for (int o = 0; o < N_OUT; ++o) {
        lg[o] = fmaf(s[o], invs, b2[o]);
        mx = fmaxf(mx, lg[o]);
    }
    float se = 0.f;
    #pragma unroll
    for (int o = 0; o < N_OUT; ++o) se += expf(lg[o] - mx);
    const float lse = logf(se) + mx;
    float* op = out + (size_t)b * N_OUT;
    #pragma unroll
    for (int o = 0; o < N_OUT; ++o) op[o] = lg[o] - lse;
}

extern "C" void kernel_launch(void* const* d_in, const int* in_sizes, int n_in,
                              void* d_out, int out_size, void* d_ws, size_t ws_size,
                              hipStream_t stream) {
    const float* x  = (const float*)d_in[0];
    const float* w1 = (const float*)d_in[1];
    const float* b1 = (const float*)d_in[2];
    const float* w2 = (const float*)d_in[3];
    const float* b2 = (const float*)d_in[4];
    float* out = (float*)d_out;

    char* ws = (char*)d_ws;
    u16* xb  = (u16*)(ws);                            // 13,107,200 B
    float* part = (float*)(ws);                       // 10,485,760 B (overlay, dead xb)
    u16* w1b = (u16*)(ws + 13107200);                 //  6,553,600 B
    u16* ht  = (u16*)(ws + 19660800);                 // 67,108,864 B
    signed char* w2c = (signed char*)(ws + 86769664); //     65,536 B
    u32* maxb = (u32*)(ws + 86835200);                //          4 B

    prep_all<<<4816, 256, 0, stream>>>(x, w1, w2, xb, w1b, w2c, maxb);
    gemm1<<<dim3(32, 32), 256, 0, stream>>>(xb, w1b, b1, ht, maxb);
    gemm2_part<<<dim3(16, 32), 256, 0, stream>>>(ht, w2c, maxb, part);
    lsm_out<<<32, 256, 0, stream>>>(part, b2, maxb, out);
}